// Round 23
// baseline (138.375 us; speedup 1.0000x reference)
//
#include <hip/hip_runtime.h>

// Problem constants (from reference)
#define NN 4096
#define CC 128
#define II 9
#define DD 9
#define EE 10
#define PP3 23
#define PP2 5
#define PP1 3
// symmetric monomial counts over 9 vars
#define F3 165   // i<=j<=k
#define F2 45    // i<=j
#define F1 9
#define FTOT (F3 + F2 + F1)  // 219
#define FPAD 224             // padded K (14 x 16)
#define NKT14 14             // K-tiles of 16 (32x32x16 MFMA)

// workspace layout (bytes)
#define CUR_OFF 0
#define LIST_OFF (CUR_OFF + 64)                // 16 ints + pad
#define WG16_OFF (LIST_OFF + NN * EE * 4)      // f16 W images: E*C*9*224*2 = 5.2 MB

#define CPB 4      // channels per block (1 per wave) — r14 best-known config
#define TS 8       // tile-stride — 2560 blocks
#define WBLK 126   // wprep blocks (16 fd each, 126*16 = 2016 = 9*FPAD)

typedef _Float16 f16x8 __attribute__((ext_vector_type(8)));
typedef __fp16 fp16x2 __attribute__((ext_vector_type(2)));   // cvt_pkrtz return type
typedef float f32x16 __attribute__((ext_vector_type(16)));

static __device__ __forceinline__ unsigned pkrtz(float a, float b) {
    fp16x2 h = __builtin_amdgcn_cvt_pkrtz(a, b);
    return __builtin_bit_cast(unsigned, h);
}

static __device__ __forceinline__ unsigned short h16(float a) {
    _Float16 ha = (_Float16)a;
    return __builtin_bit_cast(unsigned short, ha);
}

// prep kernel (r22, unchanged). Block 0: bucketing via LDS atomics (the
// r21 ~40us residual was 4096 device-scope atomicAdds to ONE 64B line,
// serialized across 8 XCDs; LDS atomics are DS-unit-local). List ORDER
// nondeterministic but node results are slot-independent -> d_out
// bit-deterministic. Blocks 1..126: wprep — symmetrize 16 fd into LDS,
// contract vs register w-tables, LDS-transpose staging -> dword stores.
__global__ __launch_bounds__(256) void prep_kernel(
    const float* __restrict__ u3,
    const float* __restrict__ u2,
    const float* __restrict__ u1,
    const float* __restrict__ w3,
    const float* __restrict__ w2,
    const float* __restrict__ w1,
    const int* __restrict__ indices,
    int* __restrict__ cursors,
    int* __restrict__ lists,
    unsigned short* __restrict__ Wg16)
{
    const int tid = threadIdx.x;

    if (blockIdx.x == 0) {
        __shared__ int lCnt[16];
        if (tid < 16) lCnt[tid] = 0;
        __syncthreads();
        #pragma unroll
        for (int it = 0; it < NN / 256; it++) {
            const int b = it * 256 + tid;
            const int e = indices[b];
            const int slot = atomicAdd(&lCnt[e], 1);
            lists[e * NN + slot] = b;
        }
        __syncthreads();
        if (tid < 16) cursors[tid] = lCnt[tid];
        return;
    }

    const int fd0 = (blockIdx.x - 1) * 16;
    __shared__ float sSu[16 * 23];               // symmetrized su for these fd
    __shared__ unsigned short sT[2 * CC * 18];   // transpose staging (2 species)

    // ---- Phase A: symmetrize ----
    for (int idx = tid; idx < 16 * 23; idx += 256) {
        const int l = idx / 23, p = idx % 23;
        const int fd = fd0 + l;
        const int d = fd / FPAD;
        const int f = fd - d * FPAD;
        float s = 0.f;
        if (f < F3) {
            int I0 = 0, J0 = 0, K0 = 0;
            {
                int rem = f;
                bool fo = false;
                for (int i = 0; i < 9 && !fo; i++)
                    for (int j = i; j < 9 && !fo; j++) {
                        int cnt = 9 - j;
                        if (rem < cnt) { I0 = i; J0 = j; K0 = j + rem; fo = true; }
                        else rem -= cnt;
                    }
            }
            int a[3] = {I0, J0, K0};
            const int ord[6][3] = {{0,1,2},{0,2,1},{1,0,2},{1,2,0},{2,0,1},{2,1,0}};
            int codes[6];
            int np = 0;
            for (int q = 0; q < 6; q++) {
                int ii = a[ord[q][0]], jj = a[ord[q][1]], kk = a[ord[q][2]];
                int code = (ii * 9 + jj) * 9 + kk;
                bool seen = false;
                for (int r2 = 0; r2 < np; r2++) if (codes[r2] == code) seen = true;
                if (!seen) {
                    codes[np++] = code;
                    s += u3[((((d * 9 + ii) * 9 + jj) * 9 + kk)) * PP3 + p];
                }
            }
        } else if (f < F3 + F2) {
            if (p < PP2) {
                const int t2 = f - F3;
                int I0 = 0, J0 = 0;
                {
                    int rem = t2;
                    bool fo = false;
                    for (int i = 0; i < 9 && !fo; i++) {
                        int cnt = 9 - i;
                        if (rem < cnt) { I0 = i; J0 = i + rem; fo = true; }
                        else rem -= cnt;
                    }
                }
                s = u2[(((d * 9 + I0) * 9 + J0) * PP2) + p];
                if (I0 != J0) s += u2[(((d * 9 + J0) * 9 + I0) * PP2) + p];
            }
        } else if (f < FTOT) {
            if (p < PP1) s = u1[(d * 9 + (f - F3 - F2)) * PP1 + p];
        }
        sSu[idx] = s;
    }
    __syncthreads();

    // ---- Phase B: contract vs w-tables, 2 species per pass ----
    const int c = tid & 127;
    const int sub = tid >> 7;   // wave-uniform
    unsigned* dst = reinterpret_cast<unsigned*>(Wg16);

    for (int eit = 0; eit < 5; eit++) {
        const int e = eit * 2 + sub;
        float wv3[PP3];
        #pragma unroll
        for (int p = 0; p < PP3; p++) wv3[p] = w3[(e * PP3 + p) * CC + c];
        float wv2[PP2];
        #pragma unroll
        for (int p = 0; p < PP2; p++) wv2[p] = w2[(e * PP2 + p) * CC + c];
        float wv1[PP1];
        #pragma unroll
        for (int p = 0; p < PP1; p++) wv1[p] = w1[(e * PP1 + p) * CC + c];

        #pragma unroll
        for (int l = 0; l < 16; l++) {
            const int fd = fd0 + l;
            const int d = fd / FPAD;
            const int f = fd - d * FPAD;
            float v = 0.f;
            if (f < F3) {
                #pragma unroll
                for (int p = 0; p < PP3; p++) v += sSu[l * 23 + p] * wv3[p];
            } else if (f < F3 + F2) {
                #pragma unroll
                for (int p = 0; p < PP2; p++) v += sSu[l * 23 + p] * wv2[p];
            } else if (f < FTOT) {
                #pragma unroll
                for (int p = 0; p < PP1; p++) v += sSu[l * 23 + p] * wv1[p];
            }
            sT[(sub * CC + c) * 18 + l] = h16(v);
        }
        __syncthreads();

        for (int q = tid; q < 2 * CC * 8; q += 256) {
            const int se = q >> 10;          // q / (CC*8)
            const int cc = (q >> 3) & 127;
            const int dw = q & 7;
            const int ee = eit * 2 + se;
            const unsigned lo = sT[(se * CC + cc) * 18 + dw * 2];
            const unsigned hi = sT[(se * CC + cc) * 18 + dw * 2 + 1];
            dst[(size_t)(ee * CC + cc) * (9 * FPAD / 2) + fd0 / 2 + dw] = lo | (hi << 16);
        }
        __syncthreads();
    }
}

// Main kernel — r14 body; r23 change: __launch_bounds__(256, 8).
// VGPR=64 is exactly the 8-wave/SIMD budget (512/8); the old (256,4)
// capped residency at 16 waves/CU (50%) and measured occupancy was 33%
// with VALUBusy 24% — latency-bound with a self-imposed occupancy cap.
__global__ __launch_bounds__(256, 8) void symcon_reg32_kernel(
    const float* __restrict__ x,
    const unsigned short* __restrict__ Wg16,
    const int* __restrict__ cursors,
    const int* __restrict__ lists,
    float* __restrict__ out)
{
    const int e = blockIdx.y;
    const int lane = threadIdx.x & 63;
    const int wid = threadIdx.x >> 6;
    const int c = blockIdx.x * CPB + wid;
    const int r = lane & 31;       // node row within tile; also B col (= d)
    const int g = lane >> 5;       // k-half
    const bool isg1 = (g == 1);

    // B fragments: lane holds B[k = t*16 + g*8 + j][col = r], zeros for col>=9
    f16x8 bfrag[NKT14];
    {
        const unsigned short* wp = Wg16 + (size_t)(e * CC + c) * (9 * FPAD);
        #pragma unroll
        for (int t = 0; t < NKT14; t++) {
            f16x8 v = {0, 0, 0, 0, 0, 0, 0, 0};
            if (r < 9)
                v = *reinterpret_cast<const f16x8*>(wp + r * FPAD + t * 16 + g * 8);
            bfrag[t] = v;
        }
    }

    const int cnt = cursors[e];
    const int ntiles = (cnt + 31) >> 5;
    const int* lbase = lists + e * NN;
    float* outc = out + (size_t)c * DD;

    int T = blockIdx.z;
    int nb_cur, nb_next;
    float xv[9];
    {
        const int n = T * 32 + r;
        const bool valid = (T < ntiles) && (n < cnt);
        nb_cur = valid ? lbase[n] : 0;
        const float* xr = x + ((size_t)nb_cur * CC + c) * II;
        #pragma unroll
        for (int q = 0; q < 9; q++) xv[q] = valid ? xr[q] : 0.f;
    }
    {
        const int n = (T + TS) * 32 + r;
        const bool valid = (T + TS < ntiles) && (n < cnt);
        nb_next = valid ? lbase[n] : 0;
    }

    while (T < ntiles) {
        // ---- independent prefetches: x row for T+TS (id already in hand),
        //      id for T+2*TS ----
        float xn[9];
        {
            const int n = (T + TS) * 32 + r;
            const bool valid = (T + TS < ntiles) && (n < cnt);
            const float* xr = x + ((size_t)nb_next * CC + c) * II;
            #pragma unroll
            for (int q = 0; q < 9; q++) xn[q] = valid ? xr[q] : 0.f;
        }
        int nb_next2;
        {
            const int n = (T + 2 * TS) * 32 + r;
            const bool valid = (T + 2 * TS < ntiles) && (n < cnt);
            nb_next2 = valid ? lbase[n] : 0;
        }

        // ---- monomial stream with interleaved MFMA ----
        f32x16 acc = {0.f, 0.f, 0.f, 0.f, 0.f, 0.f, 0.f, 0.f,
                      0.f, 0.f, 0.f, 0.f, 0.f, 0.f, 0.f, 0.f};
        unsigned au[4];
        {
            float pend = 0.f;
            int F = 0;
            // Pair P = F>>1: K-tile t = P>>3, q = P&7, dword jd = q&3 — all
            // compile-time after unroll. q<4 writes unconditional (g1 lanes
            // overwritten by their q>=4 select). At q==7 fragment complete
            // -> MFMA.
#define EMITR(expr) { const float _m = (expr);                                \
            if (F & 1) { const unsigned _pk = pkrtz(pend, _m);                \
                const int _P = F >> 1; const int _t = _P >> 3;                \
                const int _q = _P & 7; const int _jd = _q & 3;                \
                if (_q < 4) au[_jd] = _pk;                                    \
                else        au[_jd] = isg1 ? _pk : au[_jd];                   \
                if (_q == 7) {                                                \
                    f16x8 af;                                                 \
                    unsigned* _ap = reinterpret_cast<unsigned*>(&af);         \
                    _ap[0] = au[0]; _ap[1] = au[1];                           \
                    _ap[2] = au[2]; _ap[3] = au[3];                           \
                    acc = __builtin_amdgcn_mfma_f32_32x32x16_f16(             \
                        af, bfrag[_t], acc, 0, 0, 0);                         \
                }                                                             \
            } else pend = _m; F++; }
            #pragma unroll
            for (int i = 0; i < 9; i++)
                #pragma unroll
                for (int j = i; j < 9; j++) {
                    const float xij = xv[i] * xv[j];
                    #pragma unroll
                    for (int k = j; k < 9; k++)
                        EMITR(xij * xv[k])
                }
            #pragma unroll
            for (int i = 0; i < 9; i++)
                #pragma unroll
                for (int j = i; j < 9; j++)
                    EMITR(xv[i] * xv[j])
            #pragma unroll
            for (int i = 0; i < 9; i++)
                EMITR(xv[i])
            #pragma unroll
            for (int z = 0; z < 5; z++)   // zero-pad f 219..223 (exactly 224)
                EMITR(0.f)
#undef EMITR
        }

        // ---- scatter D: col = r (= d), row = (reg&3) + 8*(reg>>2) + 4*g.
        // Node id for row comes from lane 'row' via shfl (all lanes
        // participate; store guarded afterwards). ----
        #pragma unroll
        for (int reg = 0; reg < 16; reg++) {
            const int row = (reg & 3) + 8 * (reg >> 2) + 4 * g;
            const int sb = __shfl(nb_cur, row);
            const int slot = T * 32 + row;
            if (r < 9 && slot < cnt)
                outc[(size_t)sb * (CC * DD) + r] = acc[reg];
        }

        #pragma unroll
        for (int q = 0; q < 9; q++) xv[q] = xn[q];
        nb_cur = nb_next;
        nb_next = nb_next2;
        T += TS;
    }
}

extern "C" void kernel_launch(void* const* d_in, const int* in_sizes, int n_in,
                              void* d_out, int out_size, void* d_ws, size_t ws_size,
                              hipStream_t stream) {
    const float* x   = (const float*)d_in[0];
    const int* indices = (const int*)d_in[1];
    const float* u3  = (const float*)d_in[2];
    const float* u2  = (const float*)d_in[3];
    const float* u1  = (const float*)d_in[4];
    const float* w3  = (const float*)d_in[5];
    const float* w2  = (const float*)d_in[6];
    const float* w1  = (const float*)d_in[7];
    float* out = (float*)d_out;

    char* ws = (char*)d_ws;
    int* cursors = (int*)(ws + CUR_OFF);
    int* lists = (int*)(ws + LIST_OFF);
    unsigned short* Wg16 = (unsigned short*)(ws + WG16_OFF);

    hipLaunchKernelGGL(prep_kernel, dim3(WBLK + 1), dim3(256), 0, stream,
                       u3, u2, u1, w3, w2, w1, indices, cursors, lists, Wg16);
    hipLaunchKernelGGL(symcon_reg32_kernel, dim3(CC / CPB, EE, TS), dim3(256), 0, stream,
                       x, Wg16, cursors, lists, out);
}

// Round 24
// 130.207 us; speedup vs baseline: 1.0627x; 1.0627x over previous
//
#include <hip/hip_runtime.h>

// Problem constants (from reference)
#define NN 4096
#define CC 128
#define II 9
#define DD 9
#define EE 10
#define PP3 23
#define PP2 5
#define PP1 3
// symmetric monomial counts over 9 vars
#define F3 165   // i<=j<=k
#define F2 45    // i<=j
#define F1 9
#define FTOT (F3 + F2 + F1)  // 219
#define FPAD 224             // padded K (14 x 16)
#define NKT14 14             // K-tiles of 16 (32x32x16 MFMA)

// workspace layout (bytes)
#define CUR_OFF 0
#define LIST_OFF (CUR_OFF + 64)                // 16 ints + pad
#define WG16_OFF (LIST_OFF + NN * EE * 4)      // f16 W images: E*C*9*224*2 = 5.2 MB

#define CPB 4      // channels per block (1 per wave) — r14 best-known config
#define TS 8       // tile-stride — 2560 blocks
#define WBLK 126   // wprep blocks (16 fd each, 126*16 = 2016 = 9*FPAD)

typedef _Float16 f16x8 __attribute__((ext_vector_type(8)));
typedef __fp16 fp16x2 __attribute__((ext_vector_type(2)));   // cvt_pkrtz return type
typedef float f32x16 __attribute__((ext_vector_type(16)));

static __device__ __forceinline__ unsigned pkrtz(float a, float b) {
    fp16x2 h = __builtin_amdgcn_cvt_pkrtz(a, b);
    return __builtin_bit_cast(unsigned, h);
}

static __device__ __forceinline__ unsigned short h16(float a) {
    _Float16 ha = (_Float16)a;
    return __builtin_bit_cast(unsigned short, ha);
}

// prep kernel (r22, unchanged). Block 0: bucketing via LDS atomics (the
// r21 ~40us residual was 4096 device-scope atomicAdds to ONE 64B line,
// serialized across 8 XCDs; LDS atomics are DS-unit-local). List ORDER
// nondeterministic but node results are slot-independent -> d_out
// bit-deterministic. Blocks 1..126: wprep — symmetrize 16 fd into LDS,
// contract vs register w-tables, LDS-transpose staging -> dword stores.
__global__ __launch_bounds__(256) void prep_kernel(
    const float* __restrict__ u3,
    const float* __restrict__ u2,
    const float* __restrict__ u1,
    const float* __restrict__ w3,
    const float* __restrict__ w2,
    const float* __restrict__ w1,
    const int* __restrict__ indices,
    int* __restrict__ cursors,
    int* __restrict__ lists,
    unsigned short* __restrict__ Wg16)
{
    const int tid = threadIdx.x;

    if (blockIdx.x == 0) {
        __shared__ int lCnt[16];
        if (tid < 16) lCnt[tid] = 0;
        __syncthreads();
        #pragma unroll
        for (int it = 0; it < NN / 256; it++) {
            const int b = it * 256 + tid;
            const int e = indices[b];
            const int slot = atomicAdd(&lCnt[e], 1);
            lists[e * NN + slot] = b;
        }
        __syncthreads();
        if (tid < 16) cursors[tid] = lCnt[tid];
        return;
    }

    const int fd0 = (blockIdx.x - 1) * 16;
    __shared__ float sSu[16 * 23];               // symmetrized su for these fd
    __shared__ unsigned short sT[2 * CC * 18];   // transpose staging (2 species)

    // ---- Phase A: symmetrize ----
    for (int idx = tid; idx < 16 * 23; idx += 256) {
        const int l = idx / 23, p = idx % 23;
        const int fd = fd0 + l;
        const int d = fd / FPAD;
        const int f = fd - d * FPAD;
        float s = 0.f;
        if (f < F3) {
            int I0 = 0, J0 = 0, K0 = 0;
            {
                int rem = f;
                bool fo = false;
                for (int i = 0; i < 9 && !fo; i++)
                    for (int j = i; j < 9 && !fo; j++) {
                        int cnt = 9 - j;
                        if (rem < cnt) { I0 = i; J0 = j; K0 = j + rem; fo = true; }
                        else rem -= cnt;
                    }
            }
            int a[3] = {I0, J0, K0};
            const int ord[6][3] = {{0,1,2},{0,2,1},{1,0,2},{1,2,0},{2,0,1},{2,1,0}};
            int codes[6];
            int np = 0;
            for (int q = 0; q < 6; q++) {
                int ii = a[ord[q][0]], jj = a[ord[q][1]], kk = a[ord[q][2]];
                int code = (ii * 9 + jj) * 9 + kk;
                bool seen = false;
                for (int r2 = 0; r2 < np; r2++) if (codes[r2] == code) seen = true;
                if (!seen) {
                    codes[np++] = code;
                    s += u3[((((d * 9 + ii) * 9 + jj) * 9 + kk)) * PP3 + p];
                }
            }
        } else if (f < F3 + F2) {
            if (p < PP2) {
                const int t2 = f - F3;
                int I0 = 0, J0 = 0;
                {
                    int rem = t2;
                    bool fo = false;
                    for (int i = 0; i < 9 && !fo; i++) {
                        int cnt = 9 - i;
                        if (rem < cnt) { I0 = i; J0 = i + rem; fo = true; }
                        else rem -= cnt;
                    }
                }
                s = u2[(((d * 9 + I0) * 9 + J0) * PP2) + p];
                if (I0 != J0) s += u2[(((d * 9 + J0) * 9 + I0) * PP2) + p];
            }
        } else if (f < FTOT) {
            if (p < PP1) s = u1[(d * 9 + (f - F3 - F2)) * PP1 + p];
        }
        sSu[idx] = s;
    }
    __syncthreads();

    // ---- Phase B: contract vs w-tables, 2 species per pass ----
    const int c = tid & 127;
    const int sub = tid >> 7;   // wave-uniform
    unsigned* dst = reinterpret_cast<unsigned*>(Wg16);

    for (int eit = 0; eit < 5; eit++) {
        const int e = eit * 2 + sub;
        float wv3[PP3];
        #pragma unroll
        for (int p = 0; p < PP3; p++) wv3[p] = w3[(e * PP3 + p) * CC + c];
        float wv2[PP2];
        #pragma unroll
        for (int p = 0; p < PP2; p++) wv2[p] = w2[(e * PP2 + p) * CC + c];
        float wv1[PP1];
        #pragma unroll
        for (int p = 0; p < PP1; p++) wv1[p] = w1[(e * PP1 + p) * CC + c];

        #pragma unroll
        for (int l = 0; l < 16; l++) {
            const int fd = fd0 + l;
            const int d = fd / FPAD;
            const int f = fd - d * FPAD;
            float v = 0.f;
            if (f < F3) {
                #pragma unroll
                for (int p = 0; p < PP3; p++) v += sSu[l * 23 + p] * wv3[p];
            } else if (f < F3 + F2) {
                #pragma unroll
                for (int p = 0; p < PP2; p++) v += sSu[l * 23 + p] * wv2[p];
            } else if (f < FTOT) {
                #pragma unroll
                for (int p = 0; p < PP1; p++) v += sSu[l * 23 + p] * wv1[p];
            }
            sT[(sub * CC + c) * 18 + l] = h16(v);
        }
        __syncthreads();

        for (int q = tid; q < 2 * CC * 8; q += 256) {
            const int se = q >> 10;          // q / (CC*8)
            const int cc = (q >> 3) & 127;
            const int dw = q & 7;
            const int ee = eit * 2 + se;
            const unsigned lo = sT[(se * CC + cc) * 18 + dw * 2];
            const unsigned hi = sT[(se * CC + cc) * 18 + dw * 2 + 1];
            dst[(size_t)(ee * CC + cc) * (9 * FPAD / 2) + fd0 / 2 + dw] = lo | (hi << 16);
        }
        __syncthreads();
    }
}

// Main kernel — r14/r22 body; r24 change: __launch_bounds__(256, 6).
// r23 lesson: (256,8) forces a 64-VGPR budget the live set can't fit ->
// compiler allocates 32 + scratch spill (FETCH 189MB, 135us). (256,6)
// gives an 85-VGPR budget (natural allocation is 64 -> no pressure) while
// raising the residency cap 4->6 blocks/CU (16->24 waves, 50->75%).
__global__ __launch_bounds__(256, 6) void symcon_reg32_kernel(
    const float* __restrict__ x,
    const unsigned short* __restrict__ Wg16,
    const int* __restrict__ cursors,
    const int* __restrict__ lists,
    float* __restrict__ out)
{
    const int e = blockIdx.y;
    const int lane = threadIdx.x & 63;
    const int wid = threadIdx.x >> 6;
    const int c = blockIdx.x * CPB + wid;
    const int r = lane & 31;       // node row within tile; also B col (= d)
    const int g = lane >> 5;       // k-half
    const bool isg1 = (g == 1);

    // B fragments: lane holds B[k = t*16 + g*8 + j][col = r], zeros for col>=9
    f16x8 bfrag[NKT14];
    {
        const unsigned short* wp = Wg16 + (size_t)(e * CC + c) * (9 * FPAD);
        #pragma unroll
        for (int t = 0; t < NKT14; t++) {
            f16x8 v = {0, 0, 0, 0, 0, 0, 0, 0};
            if (r < 9)
                v = *reinterpret_cast<const f16x8*>(wp + r * FPAD + t * 16 + g * 8);
            bfrag[t] = v;
        }
    }

    const int cnt = cursors[e];
    const int ntiles = (cnt + 31) >> 5;
    const int* lbase = lists + e * NN;
    float* outc = out + (size_t)c * DD;

    int T = blockIdx.z;
    int nb_cur, nb_next;
    float xv[9];
    {
        const int n = T * 32 + r;
        const bool valid = (T < ntiles) && (n < cnt);
        nb_cur = valid ? lbase[n] : 0;
        const float* xr = x + ((size_t)nb_cur * CC + c) * II;
        #pragma unroll
        for (int q = 0; q < 9; q++) xv[q] = valid ? xr[q] : 0.f;
    }
    {
        const int n = (T + TS) * 32 + r;
        const bool valid = (T + TS < ntiles) && (n < cnt);
        nb_next = valid ? lbase[n] : 0;
    }

    while (T < ntiles) {
        // ---- independent prefetches: x row for T+TS (id already in hand),
        //      id for T+2*TS ----
        float xn[9];
        {
            const int n = (T + TS) * 32 + r;
            const bool valid = (T + TS < ntiles) && (n < cnt);
            const float* xr = x + ((size_t)nb_next * CC + c) * II;
            #pragma unroll
            for (int q = 0; q < 9; q++) xn[q] = valid ? xr[q] : 0.f;
        }
        int nb_next2;
        {
            const int n = (T + 2 * TS) * 32 + r;
            const bool valid = (T + 2 * TS < ntiles) && (n < cnt);
            nb_next2 = valid ? lbase[n] : 0;
        }

        // ---- monomial stream with interleaved MFMA ----
        f32x16 acc = {0.f, 0.f, 0.f, 0.f, 0.f, 0.f, 0.f, 0.f,
                      0.f, 0.f, 0.f, 0.f, 0.f, 0.f, 0.f, 0.f};
        unsigned au[4];
        {
            float pend = 0.f;
            int F = 0;
            // Pair P = F>>1: K-tile t = P>>3, q = P&7, dword jd = q&3 — all
            // compile-time after unroll. q<4 writes unconditional (g1 lanes
            // overwritten by their q>=4 select). At q==7 fragment complete
            // -> MFMA.
#define EMITR(expr) { const float _m = (expr);                                \
            if (F & 1) { const unsigned _pk = pkrtz(pend, _m);                \
                const int _P = F >> 1; const int _t = _P >> 3;                \
                const int _q = _P & 7; const int _jd = _q & 3;                \
                if (_q < 4) au[_jd] = _pk;                                    \
                else        au[_jd] = isg1 ? _pk : au[_jd];                   \
                if (_q == 7) {                                                \
                    f16x8 af;                                                 \
                    unsigned* _ap = reinterpret_cast<unsigned*>(&af);         \
                    _ap[0] = au[0]; _ap[1] = au[1];                           \
                    _ap[2] = au[2]; _ap[3] = au[3];                           \
                    acc = __builtin_amdgcn_mfma_f32_32x32x16_f16(             \
                        af, bfrag[_t], acc, 0, 0, 0);                         \
                }                                                             \
            } else pend = _m; F++; }
            #pragma unroll
            for (int i = 0; i < 9; i++)
                #pragma unroll
                for (int j = i; j < 9; j++) {
                    const float xij = xv[i] * xv[j];
                    #pragma unroll
                    for (int k = j; k < 9; k++)
                        EMITR(xij * xv[k])
                }
            #pragma unroll
            for (int i = 0; i < 9; i++)
                #pragma unroll
                for (int j = i; j < 9; j++)
                    EMITR(xv[i] * xv[j])
            #pragma unroll
            for (int i = 0; i < 9; i++)
                EMITR(xv[i])
            #pragma unroll
            for (int z = 0; z < 5; z++)   // zero-pad f 219..223 (exactly 224)
                EMITR(0.f)
#undef EMITR
        }

        // ---- scatter D: col = r (= d), row = (reg&3) + 8*(reg>>2) + 4*g.
        // Node id for row comes from lane 'row' via shfl (all lanes
        // participate; store guarded afterwards). ----
        #pragma unroll
        for (int reg = 0; reg < 16; reg++) {
            const int row = (reg & 3) + 8 * (reg >> 2) + 4 * g;
            const int sb = __shfl(nb_cur, row);
            const int slot = T * 32 + row;
            if (r < 9 && slot < cnt)
                outc[(size_t)sb * (CC * DD) + r] = acc[reg];
        }

        #pragma unroll
        for (int q = 0; q < 9; q++) xv[q] = xn[q];
        nb_cur = nb_next;
        nb_next = nb_next2;
        T += TS;
    }
}

extern "C" void kernel_launch(void* const* d_in, const int* in_sizes, int n_in,
                              void* d_out, int out_size, void* d_ws, size_t ws_size,
                              hipStream_t stream) {
    const float* x   = (const float*)d_in[0];
    const int* indices = (const int*)d_in[1];
    const float* u3  = (const float*)d_in[2];
    const float* u2  = (const float*)d_in[3];
    const float* u1  = (const float*)d_in[4];
    const float* w3  = (const float*)d_in[5];
    const float* w2  = (const float*)d_in[6];
    const float* w1  = (const float*)d_in[7];
    float* out = (float*)d_out;

    char* ws = (char*)d_ws;
    int* cursors = (int*)(ws + CUR_OFF);
    int* lists = (int*)(ws + LIST_OFF);
    unsigned short* Wg16 = (unsigned short*)(ws + WG16_OFF);

    hipLaunchKernelGGL(prep_kernel, dim3(WBLK + 1), dim3(256), 0, stream,
                       u3, u2, u1, w3, w2, w1, indices, cursors, lists, Wg16);
    hipLaunchKernelGGL(symcon_reg32_kernel, dim3(CC / CPB, EE, TS), dim3(256), 0, stream,
                       x, Wg16, cursors, lists, out);
}

// Round 25
// 83.607 us; speedup vs baseline: 1.6551x; 1.5574x over previous
//
#include <hip/hip_runtime.h>

// Problem constants (from reference)
#define NN 4096
#define CC 128
#define II 9
#define DD 9
#define EE 10
#define PP3 23
#define PP2 5
#define PP1 3
// symmetric monomial counts over 9 vars
#define F3 165   // i<=j<=k
#define F2 45    // i<=j
#define F1 9
#define FTOT (F3 + F2 + F1)  // 219
#define FPAD 224             // padded K (14 x 16)
#define NKT14 14             // K-tiles of 16 (32x32x16 MFMA)

// workspace layout (bytes)
#define CUR_OFF 0
#define LIST_OFF (CUR_OFF + 64)                // 16 ints + pad
#define WG16_OFF (LIST_OFF + NN * EE * 4)      // f16 W images: E*C*9*224*2 = 5.2 MB

#define CPB 4      // channels per block (1 per wave) — best-known config
#define TS 8       // tile-stride — 2560 blocks
#define WBLK 126   // wprep blocks (16 fd each, 126*16 = 2016 = 9*FPAD)

typedef _Float16 f16x8 __attribute__((ext_vector_type(8)));
typedef __fp16 fp16x2 __attribute__((ext_vector_type(2)));   // cvt_pkrtz return type
typedef float f32x16 __attribute__((ext_vector_type(16)));

static __device__ __forceinline__ unsigned pkrtz(float a, float b) {
    fp16x2 h = __builtin_amdgcn_cvt_pkrtz(a, b);
    return __builtin_bit_cast(unsigned, h);
}

static __device__ __forceinline__ unsigned short h16(float a) {
    _Float16 ha = (_Float16)a;
    return __builtin_bit_cast(unsigned short, ha);
}

// prep kernel (r22). Block 0: bucketing via LDS atomics (the r21 ~40us
// residual was 4096 device-scope atomicAdds to ONE 64B line, serialized
// across 8 XCDs; LDS atomics are DS-unit-local). List ORDER
// nondeterministic but node results are slot-independent -> d_out
// bit-deterministic. Blocks 1..126: wprep — symmetrize 16 fd into LDS,
// contract vs register w-tables, LDS-transpose staging -> dword stores.
__global__ __launch_bounds__(256) void prep_kernel(
    const float* __restrict__ u3,
    const float* __restrict__ u2,
    const float* __restrict__ u1,
    const float* __restrict__ w3,
    const float* __restrict__ w2,
    const float* __restrict__ w1,
    const int* __restrict__ indices,
    int* __restrict__ cursors,
    int* __restrict__ lists,
    unsigned short* __restrict__ Wg16)
{
    const int tid = threadIdx.x;

    if (blockIdx.x == 0) {
        __shared__ int lCnt[16];
        if (tid < 16) lCnt[tid] = 0;
        __syncthreads();
        #pragma unroll
        for (int it = 0; it < NN / 256; it++) {
            const int b = it * 256 + tid;
            const int e = indices[b];
            const int slot = atomicAdd(&lCnt[e], 1);
            lists[e * NN + slot] = b;
        }
        __syncthreads();
        if (tid < 16) cursors[tid] = lCnt[tid];
        return;
    }

    const int fd0 = (blockIdx.x - 1) * 16;
    __shared__ float sSu[16 * 23];               // symmetrized su for these fd
    __shared__ unsigned short sT[2 * CC * 18];   // transpose staging (2 species)

    // ---- Phase A: symmetrize ----
    for (int idx = tid; idx < 16 * 23; idx += 256) {
        const int l = idx / 23, p = idx % 23;
        const int fd = fd0 + l;
        const int d = fd / FPAD;
        const int f = fd - d * FPAD;
        float s = 0.f;
        if (f < F3) {
            int I0 = 0, J0 = 0, K0 = 0;
            {
                int rem = f;
                bool fo = false;
                for (int i = 0; i < 9 && !fo; i++)
                    for (int j = i; j < 9 && !fo; j++) {
                        int cnt = 9 - j;
                        if (rem < cnt) { I0 = i; J0 = j; K0 = j + rem; fo = true; }
                        else rem -= cnt;
                    }
            }
            int a[3] = {I0, J0, K0};
            const int ord[6][3] = {{0,1,2},{0,2,1},{1,0,2},{1,2,0},{2,0,1},{2,1,0}};
            int codes[6];
            int np = 0;
            for (int q = 0; q < 6; q++) {
                int ii = a[ord[q][0]], jj = a[ord[q][1]], kk = a[ord[q][2]];
                int code = (ii * 9 + jj) * 9 + kk;
                bool seen = false;
                for (int r2 = 0; r2 < np; r2++) if (codes[r2] == code) seen = true;
                if (!seen) {
                    codes[np++] = code;
                    s += u3[((((d * 9 + ii) * 9 + jj) * 9 + kk)) * PP3 + p];
                }
            }
        } else if (f < F3 + F2) {
            if (p < PP2) {
                const int t2 = f - F3;
                int I0 = 0, J0 = 0;
                {
                    int rem = t2;
                    bool fo = false;
                    for (int i = 0; i < 9 && !fo; i++) {
                        int cnt = 9 - i;
                        if (rem < cnt) { I0 = i; J0 = i + rem; fo = true; }
                        else rem -= cnt;
                    }
                }
                s = u2[(((d * 9 + I0) * 9 + J0) * PP2) + p];
                if (I0 != J0) s += u2[(((d * 9 + J0) * 9 + I0) * PP2) + p];
            }
        } else if (f < FTOT) {
            if (p < PP1) s = u1[(d * 9 + (f - F3 - F2)) * PP1 + p];
        }
        sSu[idx] = s;
    }
    __syncthreads();

    // ---- Phase B: contract vs w-tables, 2 species per pass ----
    const int c = tid & 127;
    const int sub = tid >> 7;   // wave-uniform
    unsigned* dst = reinterpret_cast<unsigned*>(Wg16);

    for (int eit = 0; eit < 5; eit++) {
        const int e = eit * 2 + sub;
        float wv3[PP3];
        #pragma unroll
        for (int p = 0; p < PP3; p++) wv3[p] = w3[(e * PP3 + p) * CC + c];
        float wv2[PP2];
        #pragma unroll
        for (int p = 0; p < PP2; p++) wv2[p] = w2[(e * PP2 + p) * CC + c];
        float wv1[PP1];
        #pragma unroll
        for (int p = 0; p < PP1; p++) wv1[p] = w1[(e * PP1 + p) * CC + c];

        #pragma unroll
        for (int l = 0; l < 16; l++) {
            const int fd = fd0 + l;
            const int d = fd / FPAD;
            const int f = fd - d * FPAD;
            float v = 0.f;
            if (f < F3) {
                #pragma unroll
                for (int p = 0; p < PP3; p++) v += sSu[l * 23 + p] * wv3[p];
            } else if (f < F3 + F2) {
                #pragma unroll
                for (int p = 0; p < PP2; p++) v += sSu[l * 23 + p] * wv2[p];
            } else if (f < FTOT) {
                #pragma unroll
                for (int p = 0; p < PP1; p++) v += sSu[l * 23 + p] * wv1[p];
            }
            sT[(sub * CC + c) * 18 + l] = h16(v);
        }
        __syncthreads();

        for (int q = tid; q < 2 * CC * 8; q += 256) {
            const int se = q >> 10;          // q / (CC*8)
            const int cc = (q >> 3) & 127;
            const int dw = q & 7;
            const int ee = eit * 2 + se;
            const unsigned lo = sT[(se * CC + cc) * 18 + dw * 2];
            const unsigned hi = sT[(se * CC + cc) * 18 + dw * 2 + 1];
            dst[(size_t)(ee * CC + cc) * (9 * FPAD / 2) + fd0 / 2 + dw] = lo | (hi << 16);
        }
        __syncthreads();
    }
}

// Main kernel — r14/r22 body with __launch_bounds__(256, 4), the ONLY
// budget that does not spill (r23: (256,8) -> VGPR 32 + spill, 135us;
// r24: (256,6) -> VGPR 40 + spill, 125us; natural allocation at budget
// 128 is 64 VGPR, zero scratch). Occupancy is NOT resource-capped here —
// launch_bounds' 2nd arg is a compiler guarantee, not a residency cap;
// measured 33% is tail/imbalance time-averaging.
__global__ __launch_bounds__(256, 4) void symcon_reg32_kernel(
    const float* __restrict__ x,
    const unsigned short* __restrict__ Wg16,
    const int* __restrict__ cursors,
    const int* __restrict__ lists,
    float* __restrict__ out)
{
    const int e = blockIdx.y;
    const int lane = threadIdx.x & 63;
    const int wid = threadIdx.x >> 6;
    const int c = blockIdx.x * CPB + wid;
    const int r = lane & 31;       // node row within tile; also B col (= d)
    const int g = lane >> 5;       // k-half
    const bool isg1 = (g == 1);

    // B fragments: lane holds B[k = t*16 + g*8 + j][col = r], zeros for col>=9
    f16x8 bfrag[NKT14];
    {
        const unsigned short* wp = Wg16 + (size_t)(e * CC + c) * (9 * FPAD);
        #pragma unroll
        for (int t = 0; t < NKT14; t++) {
            f16x8 v = {0, 0, 0, 0, 0, 0, 0, 0};
            if (r < 9)
                v = *reinterpret_cast<const f16x8*>(wp + r * FPAD + t * 16 + g * 8);
            bfrag[t] = v;
        }
    }

    const int cnt = cursors[e];
    const int ntiles = (cnt + 31) >> 5;
    const int* lbase = lists + e * NN;
    float* outc = out + (size_t)c * DD;

    int T = blockIdx.z;
    int nb_cur, nb_next;
    float xv[9];
    {
        const int n = T * 32 + r;
        const bool valid = (T < ntiles) && (n < cnt);
        nb_cur = valid ? lbase[n] : 0;
        const float* xr = x + ((size_t)nb_cur * CC + c) * II;
        #pragma unroll
        for (int q = 0; q < 9; q++) xv[q] = valid ? xr[q] : 0.f;
    }
    {
        const int n = (T + TS) * 32 + r;
        const bool valid = (T + TS < ntiles) && (n < cnt);
        nb_next = valid ? lbase[n] : 0;
    }

    while (T < ntiles) {
        // ---- independent prefetches: x row for T+TS (id already in hand),
        //      id for T+2*TS ----
        float xn[9];
        {
            const int n = (T + TS) * 32 + r;
            const bool valid = (T + TS < ntiles) && (n < cnt);
            const float* xr = x + ((size_t)nb_next * CC + c) * II;
            #pragma unroll
            for (int q = 0; q < 9; q++) xn[q] = valid ? xr[q] : 0.f;
        }
        int nb_next2;
        {
            const int n = (T + 2 * TS) * 32 + r;
            const bool valid = (T + 2 * TS < ntiles) && (n < cnt);
            nb_next2 = valid ? lbase[n] : 0;
        }

        // ---- monomial stream with interleaved MFMA ----
        f32x16 acc = {0.f, 0.f, 0.f, 0.f, 0.f, 0.f, 0.f, 0.f,
                      0.f, 0.f, 0.f, 0.f, 0.f, 0.f, 0.f, 0.f};
        unsigned au[4];
        {
            float pend = 0.f;
            int F = 0;
            // Pair P = F>>1: K-tile t = P>>3, q = P&7, dword jd = q&3 — all
            // compile-time after unroll. q<4 writes unconditional (g1 lanes
            // overwritten by their q>=4 select). At q==7 fragment complete
            // -> MFMA.
#define EMITR(expr) { const float _m = (expr);                                \
            if (F & 1) { const unsigned _pk = pkrtz(pend, _m);                \
                const int _P = F >> 1; const int _t = _P >> 3;                \
                const int _q = _P & 7; const int _jd = _q & 3;                \
                if (_q < 4) au[_jd] = _pk;                                    \
                else        au[_jd] = isg1 ? _pk : au[_jd];                   \
                if (_q == 7) {                                                \
                    f16x8 af;                                                 \
                    unsigned* _ap = reinterpret_cast<unsigned*>(&af);         \
                    _ap[0] = au[0]; _ap[1] = au[1];                           \
                    _ap[2] = au[2]; _ap[3] = au[3];                           \
                    acc = __builtin_amdgcn_mfma_f32_32x32x16_f16(             \
                        af, bfrag[_t], acc, 0, 0, 0);                         \
                }                                                             \
            } else pend = _m; F++; }
            #pragma unroll
            for (int i = 0; i < 9; i++)
                #pragma unroll
                for (int j = i; j < 9; j++) {
                    const float xij = xv[i] * xv[j];
                    #pragma unroll
                    for (int k = j; k < 9; k++)
                        EMITR(xij * xv[k])
                }
            #pragma unroll
            for (int i = 0; i < 9; i++)
                #pragma unroll
                for (int j = i; j < 9; j++)
                    EMITR(xv[i] * xv[j])
            #pragma unroll
            for (int i = 0; i < 9; i++)
                EMITR(xv[i])
            #pragma unroll
            for (int z = 0; z < 5; z++)   // zero-pad f 219..223 (exactly 224)
                EMITR(0.f)
#undef EMITR
        }

        // ---- scatter D: col = r (= d), row = (reg&3) + 8*(reg>>2) + 4*g.
        // Node id for row comes from lane 'row' via shfl (all lanes
        // participate; store guarded afterwards). ----
        #pragma unroll
        for (int reg = 0; reg < 16; reg++) {
            const int row = (reg & 3) + 8 * (reg >> 2) + 4 * g;
            const int sb = __shfl(nb_cur, row);
            const int slot = T * 32 + row;
            if (r < 9 && slot < cnt)
                outc[(size_t)sb * (CC * DD) + r] = acc[reg];
        }

        #pragma unroll
        for (int q = 0; q < 9; q++) xv[q] = xn[q];
        nb_cur = nb_next;
        nb_next = nb_next2;
        T += TS;
    }
}

extern "C" void kernel_launch(void* const* d_in, const int* in_sizes, int n_in,
                              void* d_out, int out_size, void* d_ws, size_t ws_size,
                              hipStream_t stream) {
    const float* x   = (const float*)d_in[0];
    const int* indices = (const int*)d_in[1];
    const float* u3  = (const float*)d_in[2];
    const float* u2  = (const float*)d_in[3];
    const float* u1  = (const float*)d_in[4];
    const float* w3  = (const float*)d_in[5];
    const float* w2  = (const float*)d_in[6];
    const float* w1  = (const float*)d_in[7];
    float* out = (float*)d_out;

    char* ws = (char*)d_ws;
    int* cursors = (int*)(ws + CUR_OFF);
    int* lists = (int*)(ws + LIST_OFF);
    unsigned short* Wg16 = (unsigned short*)(ws + WG16_OFF);

    hipLaunchKernelGGL(prep_kernel, dim3(WBLK + 1), dim3(256), 0, stream,
                       u3, u2, u1, w3, w2, w1, indices, cursors, lists, Wg16);
    hipLaunchKernelGGL(symcon_reg32_kernel, dim3(CC / CPB, EE, TS), dim3(256), 0, stream,
                       x, Wg16, cursors, lists, out);
}